// Round 2
// baseline (96.564 us; speedup 1.0000x reference)
//
#include <hip/hip_runtime.h>

constexpr int IN_DIM     = 4 * 64 * 64;  // 16384
constexpr int OUT_CH     = 2;
constexpr int NT         = 50;           // timesteps
constexpr int G          = 8;            // samples per compute block (share one W)
constexpr int BLOCK      = 512;
constexpr int ITERS      = IN_DIM / 4 / BLOCK;  // 8 float4 per thread
constexpr int MAX_CHUNKS = 1024;         // >= NT + B/G for B=4096

// d_ws int layout:
//   [0]                      nchunks
//   [1 .. 1+3*MAX_CHUNKS)    chunk table: (timestep_idx, start, len) triples
//   [1+3*MAX_CHUNKS .. +B)   order[] : sample ids sorted by bucket

__global__ void build_chunks_kernel(const int* __restrict__ t, int B, int* __restrict__ ws) {
    __shared__ int counts[NT];
    __shared__ int offs[NT + 1];
    __shared__ int cursor[NT];
    const int tid = threadIdx.x;

    if (tid < NT) counts[tid] = 0;
    __syncthreads();
    for (int b = tid; b < B; b += blockDim.x) {
        const int idx = (980 - t[b]) / 20;
        atomicAdd(&counts[idx], 1);
    }
    __syncthreads();
    if (tid == 0) {
        int acc = 0;
        for (int i = 0; i < NT; ++i) { offs[i] = acc; acc += counts[i]; }
        offs[NT] = acc;
    }
    __syncthreads();
    if (tid < NT) cursor[tid] = 0;
    __syncthreads();

    int* order = ws + 1 + 3 * MAX_CHUNKS;
    for (int b = tid; b < B; b += blockDim.x) {
        const int idx = (980 - t[b]) / 20;
        const int pos = offs[idx] + atomicAdd(&cursor[idx], 1);
        order[pos] = b;
    }

    if (tid == 0) {
        int* tab = ws + 1;
        int nc = 0;
        for (int i = 0; i < NT; ++i) {
            const int s = offs[i], e = offs[i + 1];
            for (int c = s; c < e; c += G) {
                tab[3 * nc + 0] = i;
                tab[3 * nc + 1] = c;
                tab[3 * nc + 2] = (e - c < G) ? (e - c) : G;
                ++nc;
            }
        }
        ws[0] = nc;
    }
}

__global__ __launch_bounds__(BLOCK) void dot_kernel(
    const float* __restrict__ x,     // [B, IN_DIM]
    const float* __restrict__ W,     // [NT, OUT_CH, IN_DIM]
    const float* __restrict__ bias,  // [NT, OUT_CH]
    float*       __restrict__ out,   // [B, OUT_CH]
    const int*   __restrict__ ws)
{
    const int nc = ws[0];
    const int bid = blockIdx.x;
    if (bid >= nc) return;

    const int* tab   = ws + 1;
    const int  tsidx = tab[3 * bid + 0];
    const int  start = tab[3 * bid + 1];
    const int  len   = tab[3 * bid + 2];
    const int* order = ws + 1 + 3 * MAX_CHUNKS;

    const int tid = threadIdx.x;

    int sid[G];
#pragma unroll
    for (int s = 0; s < G; ++s)
        sid[s] = order[start + (s < len ? s : len - 1)];  // duplicate last on tail

    const float4* w0 = reinterpret_cast<const float4*>(W + (size_t)tsidx * OUT_CH * IN_DIM);
    const float4* w1 = w0 + IN_DIM / 4;
    const float4* xp[G];
#pragma unroll
    for (int s = 0; s < G; ++s)
        xp[s] = reinterpret_cast<const float4*>(x + (size_t)sid[s] * IN_DIM);

    float acc[G][2] = {};
#pragma unroll
    for (int i = 0; i < ITERS; ++i) {
        const int j = tid + i * BLOCK;
        const float4 a = w0[j];
        const float4 c = w1[j];
#pragma unroll
        for (int s = 0; s < G; ++s) {
            const float4 xv = xp[s][j];
            acc[s][0] += xv.x * a.x + xv.y * a.y + xv.z * a.z + xv.w * a.w;
            acc[s][1] += xv.x * c.x + xv.y * c.y + xv.z * c.z + xv.w * c.w;
        }
    }

    // wave(64) butterfly reduce for all G*2 accumulators
#pragma unroll
    for (int s = 0; s < G; ++s) {
        for (int off = 32; off > 0; off >>= 1) {
            acc[s][0] += __shfl_down(acc[s][0], off, 64);
            acc[s][1] += __shfl_down(acc[s][1], off, 64);
        }
    }

    __shared__ float red[BLOCK / 64][G][2];
    const int wave = tid >> 6;
    if ((tid & 63) == 0) {
#pragma unroll
        for (int s = 0; s < G; ++s) {
            red[wave][s][0] = acc[s][0];
            red[wave][s][1] = acc[s][1];
        }
    }
    __syncthreads();

    if (tid < G * OUT_CH) {
        const int s  = tid >> 1;
        const int ch = tid & 1;
        if (s < len) {
            float sum = 0.0f;
#pragma unroll
            for (int w = 0; w < BLOCK / 64; ++w) sum += red[w][s][ch];
            out[(size_t)sid[s] * OUT_CH + ch] = sum + bias[tsidx * OUT_CH + ch];
        }
    }
}

extern "C" void kernel_launch(void* const* d_in, const int* in_sizes, int n_in,
                              void* d_out, int out_size, void* d_ws, size_t ws_size,
                              hipStream_t stream) {
    const float* x    = (const float*)d_in[0];
    const int*   t    = (const int*)d_in[1];
    const float* W    = (const float*)d_in[2];
    const float* bias = (const float*)d_in[3];
    float*       out  = (float*)d_out;
    int*         ws   = (int*)d_ws;

    const int B = in_sizes[1];  // 4096
    const int max_chunks = NT + (B + G - 1) / G;  // <= MAX_CHUNKS

    build_chunks_kernel<<<1, 256, 0, stream>>>(t, B, ws);
    dot_kernel<<<max_chunks, BLOCK, 0, stream>>>(x, W, bias, out, ws);
}

// Round 3
// 66.679 us; speedup vs baseline: 1.4482x; 1.4482x over previous
//
#include <hip/hip_runtime.h>

constexpr int IN_DIM  = 4 * 64 * 64;   // 16384
constexpr int OUT_CH  = 2;
constexpr int NT      = 50;
constexpr int BLOCK   = 256;
constexpr int NGROUPS = IN_DIM / 4;    // 4096 groups of 4 elements
constexpr int ITERS   = NGROUPS / BLOCK;  // 16
constexpr size_t WB_BYTES = (size_t)NT * OUT_CH * IN_DIM * 2;  // 3.125 MiB bf16

__device__ __forceinline__ unsigned short f2bf_rn(float f) {
    unsigned int u = __float_as_uint(f);
    u += 0x7FFFu + ((u >> 16) & 1u);   // round-to-nearest-even
    return (unsigned short)(u >> 16);
}

// Repack W [NT][2][IN_DIM] fp32 -> bf16, channel-interleaved per 4-element group:
// Wb[ts] groups of 8 ushorts: {ch0 e0..e3, ch1 e0..e3} -> one uint4 load serves both channels.
__global__ __launch_bounds__(BLOCK) void convert_w_kernel(
    const float* __restrict__ W, unsigned short* __restrict__ Wb)
{
    const int g = blockIdx.x * BLOCK + threadIdx.x;   // [0, NT*NGROUPS)
    if (g >= NT * NGROUPS) return;
    const int ts = g / NGROUPS;
    const int j  = g - ts * NGROUPS;
    const float* base = W + (size_t)ts * OUT_CH * IN_DIM;
    const float4 a = *reinterpret_cast<const float4*>(base + j * 4);
    const float4 c = *reinterpret_cast<const float4*>(base + IN_DIM + j * 4);
    ushort4 lo, hi;
    lo.x = f2bf_rn(a.x); lo.y = f2bf_rn(a.y); lo.z = f2bf_rn(a.z); lo.w = f2bf_rn(a.w);
    hi.x = f2bf_rn(c.x); hi.y = f2bf_rn(c.y); hi.z = f2bf_rn(c.z); hi.w = f2bf_rn(c.w);
    ushort4* dst = reinterpret_cast<ushort4*>(Wb + (size_t)ts * OUT_CH * IN_DIM) + (size_t)j * 2;
    dst[0] = lo;
    dst[1] = hi;
}

__global__ __launch_bounds__(BLOCK) void dot_bf16w_kernel(
    const float* __restrict__ x,             // [B, IN_DIM] fp32
    const int*   __restrict__ t,             // [B]
    const unsigned short* __restrict__ Wb,   // packed bf16 weights
    const float* __restrict__ bias,          // [NT, 2] fp32
    float*       __restrict__ out)           // [B, 2]
{
    const int b   = blockIdx.x;
    const int tid = threadIdx.x;
    const int idx = (980 - t[b]) / 20;

    const float4* xv = reinterpret_cast<const float4*>(x + (size_t)b * IN_DIM);
    const uint4*  wv = reinterpret_cast<const uint4*>(Wb + (size_t)idx * OUT_CH * IN_DIM);

    float acc0 = 0.0f, acc1 = 0.0f;
#pragma unroll
    for (int i = 0; i < ITERS; ++i) {
        const int j = tid + i * BLOCK;
        const float4 xv4 = xv[j];
        const uint4  w   = wv[j];
        const float a0 = __uint_as_float(w.x << 16);
        const float a1 = __uint_as_float(w.x & 0xFFFF0000u);
        const float a2 = __uint_as_float(w.y << 16);
        const float a3 = __uint_as_float(w.y & 0xFFFF0000u);
        const float c0 = __uint_as_float(w.z << 16);
        const float c1 = __uint_as_float(w.z & 0xFFFF0000u);
        const float c2 = __uint_as_float(w.w << 16);
        const float c3 = __uint_as_float(w.w & 0xFFFF0000u);
        acc0 += xv4.x * a0 + xv4.y * a1 + xv4.z * a2 + xv4.w * a3;
        acc1 += xv4.x * c0 + xv4.y * c1 + xv4.z * c2 + xv4.w * c3;
    }

    for (int off = 32; off > 0; off >>= 1) {
        acc0 += __shfl_down(acc0, off, 64);
        acc1 += __shfl_down(acc1, off, 64);
    }

    __shared__ float red[BLOCK / 64][2];
    const int wave = tid >> 6;
    if ((tid & 63) == 0) {
        red[wave][0] = acc0;
        red[wave][1] = acc1;
    }
    __syncthreads();

    if (tid == 0) {
        float s0 = red[0][0] + red[1][0] + red[2][0] + red[3][0];
        float s1 = red[0][1] + red[1][1] + red[2][1] + red[3][1];
        out[(size_t)b * OUT_CH + 0] = s0 + bias[idx * OUT_CH + 0];
        out[(size_t)b * OUT_CH + 1] = s1 + bias[idx * OUT_CH + 1];
    }
}

// Fallback (round-1 fp32 path) if d_ws is too small for the bf16 W copy.
__global__ __launch_bounds__(BLOCK) void dot_f32_kernel(
    const float* __restrict__ x, const int* __restrict__ t,
    const float* __restrict__ W, const float* __restrict__ bias,
    float* __restrict__ out)
{
    const int b   = blockIdx.x;
    const int tid = threadIdx.x;
    const int idx = (980 - t[b]) / 20;

    const float4* xv = reinterpret_cast<const float4*>(x + (size_t)b * IN_DIM);
    const float4* w0 = reinterpret_cast<const float4*>(W + (size_t)idx * OUT_CH * IN_DIM);
    const float4* w1 = w0 + IN_DIM / 4;

    float acc0 = 0.0f, acc1 = 0.0f;
#pragma unroll
    for (int i = 0; i < ITERS; ++i) {
        const int j = tid + i * BLOCK;
        const float4 xv4 = xv[j];
        const float4 a   = w0[j];
        const float4 c   = w1[j];
        acc0 += xv4.x * a.x + xv4.y * a.y + xv4.z * a.z + xv4.w * a.w;
        acc1 += xv4.x * c.x + xv4.y * c.y + xv4.z * c.z + xv4.w * c.w;
    }
    for (int off = 32; off > 0; off >>= 1) {
        acc0 += __shfl_down(acc0, off, 64);
        acc1 += __shfl_down(acc1, off, 64);
    }
    __shared__ float red[BLOCK / 64][2];
    const int wave = tid >> 6;
    if ((tid & 63) == 0) { red[wave][0] = acc0; red[wave][1] = acc1; }
    __syncthreads();
    if (tid == 0) {
        float s0 = red[0][0] + red[1][0] + red[2][0] + red[3][0];
        float s1 = red[0][1] + red[1][1] + red[2][1] + red[3][1];
        out[(size_t)b * OUT_CH + 0] = s0 + bias[idx * OUT_CH + 0];
        out[(size_t)b * OUT_CH + 1] = s1 + bias[idx * OUT_CH + 1];
    }
}

extern "C" void kernel_launch(void* const* d_in, const int* in_sizes, int n_in,
                              void* d_out, int out_size, void* d_ws, size_t ws_size,
                              hipStream_t stream) {
    const float* x    = (const float*)d_in[0];
    const int*   t    = (const int*)d_in[1];
    const float* W    = (const float*)d_in[2];
    const float* bias = (const float*)d_in[3];
    float*       out  = (float*)d_out;

    const int B = in_sizes[1];  // 4096

    if (ws_size >= WB_BYTES) {
        unsigned short* Wb = (unsigned short*)d_ws;
        const int ngrp = NT * NGROUPS;
        convert_w_kernel<<<(ngrp + BLOCK - 1) / BLOCK, BLOCK, 0, stream>>>(W, Wb);
        dot_bf16w_kernel<<<B, BLOCK, 0, stream>>>(x, t, Wb, bias, out);
    } else {
        dot_f32_kernel<<<B, BLOCK, 0, stream>>>(x, t, W, bias, out);
    }
}

// Round 5
// 58.240 us; speedup vs baseline: 1.6580x; 1.1449x over previous
//
#include <hip/hip_runtime.h>

constexpr int IN_DIM  = 4 * 64 * 64;   // 16384
constexpr int OUT_CH  = 2;
constexpr int NT      = 50;
constexpr int BLOCK   = 256;
constexpr int NGROUPS = IN_DIM / 4;    // 4096 groups of 4 elements
constexpr int ITERS   = NGROUPS / BLOCK;  // 16
constexpr size_t WB_BYTES = (size_t)NT * OUT_CH * IN_DIM * 2;  // 3.125 MiB bf16

typedef float fx4 __attribute__((ext_vector_type(4)));  // native vec for nontemporal builtin

__device__ __forceinline__ unsigned short f2bf_rn(float f) {
    unsigned int u = __float_as_uint(f);
    u += 0x7FFFu + ((u >> 16) & 1u);   // round-to-nearest-even
    return (unsigned short)(u >> 16);
}

// Repack W [NT][2][IN_DIM] fp32 -> bf16, channel-interleaved per 4-element group:
// Wb[ts] groups of 8 ushorts: {ch0 e0..e3, ch1 e0..e3} -> one uint4 load serves both channels.
__global__ __launch_bounds__(BLOCK) void convert_w_kernel(
    const float* __restrict__ W, unsigned short* __restrict__ Wb)
{
    const int g = blockIdx.x * BLOCK + threadIdx.x;   // [0, NT*NGROUPS)
    if (g >= NT * NGROUPS) return;
    const int ts = g / NGROUPS;
    const int j  = g - ts * NGROUPS;
    const float* base = W + (size_t)ts * OUT_CH * IN_DIM;
    const float4 a = *reinterpret_cast<const float4*>(base + j * 4);
    const float4 c = *reinterpret_cast<const float4*>(base + IN_DIM + j * 4);
    ushort4 lo, hi;
    lo.x = f2bf_rn(a.x); lo.y = f2bf_rn(a.y); lo.z = f2bf_rn(a.z); lo.w = f2bf_rn(a.w);
    hi.x = f2bf_rn(c.x); hi.y = f2bf_rn(c.y); hi.z = f2bf_rn(c.z); hi.w = f2bf_rn(c.w);
    ushort4* dst = reinterpret_cast<ushort4*>(Wb + (size_t)ts * OUT_CH * IN_DIM) + (size_t)j * 2;
    dst[0] = lo;
    dst[1] = hi;
}

__global__ __launch_bounds__(BLOCK) void dot_bf16w_kernel(
    const float* __restrict__ x,             // [B, IN_DIM] fp32
    const int*   __restrict__ t,             // [B]
    const unsigned short* __restrict__ Wb,   // packed bf16 weights
    const float* __restrict__ bias,          // [NT, 2] fp32
    float*       __restrict__ out)           // [B, 2]
{
    const int b   = blockIdx.x;
    const int tid = threadIdx.x;
    const int idx = (980 - t[b]) / 20;

    const fx4*   xv = reinterpret_cast<const fx4*>(x + (size_t)b * IN_DIM);
    const uint4* wv = reinterpret_cast<const uint4*>(Wb + (size_t)idx * OUT_CH * IN_DIM);

    // two partial pairs (even/odd iters) to shorten FMA dep chains
    float e0 = 0.0f, e1 = 0.0f, o0 = 0.0f, o1 = 0.0f;
#pragma unroll
    for (int i = 0; i < ITERS; i += 2) {
        const int j0 = tid + i * BLOCK;
        const int j1 = tid + (i + 1) * BLOCK;
        // x: streaming, zero reuse -> non-temporal (don't pollute L2, keep W resident)
        const fx4 xa = __builtin_nontemporal_load(&xv[j0]);
        const fx4 xb = __builtin_nontemporal_load(&xv[j1]);
        const uint4 wa = wv[j0];
        const uint4 wb = wv[j1];

        e0 += xa.x * __uint_as_float(wa.x << 16)
            + xa.y * __uint_as_float(wa.x & 0xFFFF0000u)
            + xa.z * __uint_as_float(wa.y << 16)
            + xa.w * __uint_as_float(wa.y & 0xFFFF0000u);
        e1 += xa.x * __uint_as_float(wa.z << 16)
            + xa.y * __uint_as_float(wa.z & 0xFFFF0000u)
            + xa.z * __uint_as_float(wa.w << 16)
            + xa.w * __uint_as_float(wa.w & 0xFFFF0000u);

        o0 += xb.x * __uint_as_float(wb.x << 16)
            + xb.y * __uint_as_float(wb.x & 0xFFFF0000u)
            + xb.z * __uint_as_float(wb.y << 16)
            + xb.w * __uint_as_float(wb.y & 0xFFFF0000u);
        o1 += xb.x * __uint_as_float(wb.z << 16)
            + xb.y * __uint_as_float(wb.z & 0xFFFF0000u)
            + xb.z * __uint_as_float(wb.w << 16)
            + xb.w * __uint_as_float(wb.w & 0xFFFF0000u);
    }
    float acc0 = e0 + o0;
    float acc1 = e1 + o1;

    for (int off = 32; off > 0; off >>= 1) {
        acc0 += __shfl_down(acc0, off, 64);
        acc1 += __shfl_down(acc1, off, 64);
    }

    __shared__ float red[BLOCK / 64][2];
    const int wave = tid >> 6;
    if ((tid & 63) == 0) {
        red[wave][0] = acc0;
        red[wave][1] = acc1;
    }
    __syncthreads();

    if (tid == 0) {
        float s0 = red[0][0] + red[1][0] + red[2][0] + red[3][0];
        float s1 = red[0][1] + red[1][1] + red[2][1] + red[3][1];
        out[(size_t)b * OUT_CH + 0] = s0 + bias[idx * OUT_CH + 0];
        out[(size_t)b * OUT_CH + 1] = s1 + bias[idx * OUT_CH + 1];
    }
}

// Fallback (round-1 fp32 path) if d_ws is too small for the bf16 W copy.
__global__ __launch_bounds__(BLOCK) void dot_f32_kernel(
    const float* __restrict__ x, const int* __restrict__ t,
    const float* __restrict__ W, const float* __restrict__ bias,
    float* __restrict__ out)
{
    const int b   = blockIdx.x;
    const int tid = threadIdx.x;
    const int idx = (980 - t[b]) / 20;

    const float4* xv = reinterpret_cast<const float4*>(x + (size_t)b * IN_DIM);
    const float4* w0 = reinterpret_cast<const float4*>(W + (size_t)idx * OUT_CH * IN_DIM);
    const float4* w1 = w0 + IN_DIM / 4;

    float acc0 = 0.0f, acc1 = 0.0f;
#pragma unroll
    for (int i = 0; i < ITERS; ++i) {
        const int j = tid + i * BLOCK;
        const float4 xv4 = xv[j];
        const float4 a   = w0[j];
        const float4 c   = w1[j];
        acc0 += xv4.x * a.x + xv4.y * a.y + xv4.z * a.z + xv4.w * a.w;
        acc1 += xv4.x * c.x + xv4.y * c.y + xv4.z * c.z + xv4.w * c.w;
    }
    for (int off = 32; off > 0; off >>= 1) {
        acc0 += __shfl_down(acc0, off, 64);
        acc1 += __shfl_down(acc1, off, 64);
    }
    __shared__ float red[BLOCK / 64][2];
    const int wave = tid >> 6;
    if ((tid & 63) == 0) { red[wave][0] = acc0; red[wave][1] = acc1; }
    __syncthreads();
    if (tid == 0) {
        float s0 = red[0][0] + red[1][0] + red[2][0] + red[3][0];
        float s1 = red[0][1] + red[1][1] + red[2][1] + red[3][1];
        out[(size_t)b * OUT_CH + 0] = s0 + bias[idx * OUT_CH + 0];
        out[(size_t)b * OUT_CH + 1] = s1 + bias[idx * OUT_CH + 1];
    }
}

extern "C" void kernel_launch(void* const* d_in, const int* in_sizes, int n_in,
                              void* d_out, int out_size, void* d_ws, size_t ws_size,
                              hipStream_t stream) {
    const float* x    = (const float*)d_in[0];
    const int*   t    = (const int*)d_in[1];
    const float* W    = (const float*)d_in[2];
    const float* bias = (const float*)d_in[3];
    float*       out  = (float*)d_out;
    const int B = in_sizes[1];  // 4096

    if (ws_size >= WB_BYTES) {
        unsigned short* Wb = (unsigned short*)d_ws;
        const int ngrp = NT * NGROUPS;
        convert_w_kernel<<<(ngrp + BLOCK - 1) / BLOCK, BLOCK, 0, stream>>>(W, Wb);
        dot_bf16w_kernel<<<B, BLOCK, 0, stream>>>(x, t, Wb, bias, out);
    } else {
        dot_f32_kernel<<<B, BLOCK, 0, stream>>>(x, t, W, bias, out);
    }
}